// Round 13
// baseline (146.854 us; speedup 1.0000x reference)
//
#include <hip/hip_runtime.h>
#include <hip/hip_fp16.h>
#include <math.h>

#define CC 64
#define KK 16
#define NNODES 15
#define DD 512      // input feature dim
#define MM 512      // output dim
#define NN 16384    // rows
#define KG 1024     // GEMM contraction dim = C*K

#define BM 128      // m per block (4 waves x 32)
#define BJ 64       // j per block (all waves share)

typedef _Float16 half8_t __attribute__((ext_vector_type(8)));
typedef float float4_t __attribute__((ext_vector_type(4)));

// ---------------------------------------------------------------------------
// XLA/Eigen fast-tanh for f32 (bit-exact vs JAX's jnp.tanh lowering).
// Round 3/4/5 evidence: required to match the golden's argmax codes.
// ---------------------------------------------------------------------------
__device__ __forceinline__ float xla_tanhf(float x) {
    const float kMax = 7.90531110763549805f;
    bool tiny = fabsf(x) < 0.0004f;
    float xc = fminf(fmaxf(x, -kMax), kMax);
    float x2 = __fmul_rn(xc, xc);
    float p = __fmaf_rn(x2, -2.76076847742355e-16f, 2.00018790482477e-13f);
    p = __fmaf_rn(x2, p, -8.60467152213735e-11f);
    p = __fmaf_rn(x2, p, 5.12229709037114e-08f);
    p = __fmaf_rn(x2, p, 1.48572235717979e-05f);
    p = __fmaf_rn(x2, p, 6.37261928875436e-04f);
    p = __fmaf_rn(x2, p, 4.89352455891786e-03f);
    p = __fmul_rn(xc, p);
    float q = __fmaf_rn(x2, 1.19825839466702e-06f, 1.18534705686654e-04f);
    q = __fmaf_rn(x2, q, 2.26843463243900e-03f);
    q = __fmaf_rn(x2, q, 4.89352518554385e-03f);
    return tiny ? x : __fdiv_rn(p, q);
}

// ---------------------------------------------------------------------------
// Kernel 1: elementwise fp32 -> fp16 convert of L, layout preserved (M, C*K).
// ---------------------------------------------------------------------------
__global__ __launch_bounds__(256) void convert_lut(const float* __restrict__ L,
                                                   __half* __restrict__ Lh) {
    int gid = blockIdx.x * 256 + threadIdx.x;   // over (M*KG)/4 = 131072
    float4 v = ((const float4*)L)[gid];
    __half2 a = __floats2half2_rn(v.x, v.y);
    __half2 b = __floats2half2_rn(v.z, v.w);
    ((__half2*)Lh)[2 * gid]     = a;
    ((__half2*)Lh)[2 * gid + 1] = b;
}

// ---------------------------------------------------------------------------
// Kernel 2: encode (bit-exact since round 5; conflict-free layouts r9-verified)
// ---------------------------------------------------------------------------
__global__ __launch_bounds__(256) void encode_kernel(const float* __restrict__ I,
                                                     const float* __restrict__ A,
                                                     const float* __restrict__ T,
                                                     unsigned char* __restrict__ idx) {
    __shared__ float sAT[32 * 64];     // [s*4+d][c]  transposed, conflict-free
    __shared__ float sTT[NNODES * 64]; // [i][c]      transposed, conflict-free
    const int tid = threadIdx.x;
    for (int g = tid; g < 32 * 64; g += 256)
        sAT[g] = A[((g & 63) << 5) + (g >> 6)];
    for (int g = tid; g < NNODES * 64; g += 256)
        sTT[g] = T[(g & 63) * NNODES + (g >> 6)];
    __syncthreads();

    int gid = blockIdx.x * 256 + tid;   // 0 .. N*C-1
    int j = gid >> 6;
    int c = gid & 63;

    const float* Ij = I + (size_t)j * DD + c * 8;
    float4 v0 = ((const float4*)Ij)[0];
    float4 v1 = ((const float4*)Ij)[1];
    float iv[8] = {v0.x, v0.y, v0.z, v0.w, v1.x, v1.y, v1.z, v1.w};

    float t[4] = {0.f, 0.f, 0.f, 0.f};
#pragma unroll
    for (int s = 0; s < 8; ++s) {
        float v = iv[s];
#pragma unroll
        for (int d = 0; d < 4; ++d)
            t[d] = __fmaf_rn(v, sAT[(s * 4 + d) * 64 + c], t[d]);
    }

    const int lvl[NNODES] = {0, 1, 1, 2, 2, 2, 2, 3, 3, 3, 3, 3, 3, 3, 3};
    float th[NNODES];
#pragma unroll
    for (int i = 0; i < NNODES; ++i) {
        float h = __fsub_rn(t[lvl[i]], sTT[i * 64 + c]);
        th[i] = xla_tanhf(h);
    }

    int best = 0;
    float bestv = -3.0e38f;
#pragma unroll
    for (int k = 0; k < KK; ++k) {
        int node = 0;
        float s = 0.f;
#pragma unroll
        for (int l = 0; l < 4; ++l) {
            int bit = (k >> (3 - l)) & 1;
            s = __fadd_rn(s, bit ? th[node] : -th[node]);
            node = 2 * node + 1 + bit;
        }
        if (s > bestv) { bestv = s; best = k; }   // strict >: first-max
    }
    idx[gid] = (unsigned char)best;               // coalesced byte stores
}

// ---------------------------------------------------------------------------
// Kernel 3: MFMA decode v2 — BARRIER-FREE K-loop.
// r12 lesson: 64 barriers/block at 2 blocks/CU strangled the MFMA pipeline.
// A (1 MB fp16 LUT, L2-resident, ~100% hit) is loaded DIRECTLY from global:
// a-fragment = 16B contiguous per lane; no LDS staging, no syncthreads in
// the loop. Codes staged once as u32 words, stride-17 padding (conflict-free
// staging writes and loop reads; quads broadcast same address).
// Wave tile 32m x 64j (acc 32 VGPR) -> 1024 blocks, 4 waves/SIMD.
// All fragment layouts + one-hot B build are r12-hardware-verified.
// ---------------------------------------------------------------------------
__global__ __launch_bounds__(256, 4) void gemm_decode(const __half* __restrict__ Lh,
                                                      const unsigned char* __restrict__ idx,
                                                      float* __restrict__ out) {
    __shared__ unsigned int sIdxW[BJ * 17];     // [jl][word 0..15], stride 17

    const int tid = threadIdx.x;
    const int m0 = (blockIdx.x & 3) * BM;       // 4 m-blocks
    const int j0 = (blockIdx.x >> 2) * BJ;      // 256 j-blocks

    // ---- stage codes as u32 words: sIdxW[jl*17 + s] = codes c=4s..4s+3 of row jl
    {
        const unsigned int* g = (const unsigned int*)(idx + (size_t)j0 * CC);
#pragma unroll
        for (int it = 0; it < 4; ++it) {
            int wi = it * 256 + tid;            // 0..1023
            int jl = wi >> 4;
            int s  = wi & 15;
            sIdxW[jl * 17 + s] = g[wi];         // consecutive lanes -> consecutive banks
        }
    }
    __syncthreads();                            // the ONLY barrier

    const int lane  = tid & 63;
    const int wv2   = tid >> 6;
    const int mw    = wv2 * 32;                 // wave m-offset
    const int l15   = lane & 15;
    const int quad  = lane >> 4;
    const int kpar8 = (quad & 1) * 8;
    const int chalf = quad >> 1;
    const int shft  = 8 * chalf;                // byte shift base for this quad

    float4_t acc[2][4];
#pragma unroll
    for (int rf = 0; rf < 2; ++rf)
#pragma unroll
        for (int cf = 0; cf < 4; ++cf) acc[rf][cf] = (float4_t){0.f, 0.f, 0.f, 0.f};

    const __half* abase = Lh + (size_t)(m0 + mw + l15) * KG + quad * 8;

    for (int sp = 0; sp < 16; ++sp) {           // 64 k per iter, no barriers
        // code words: lanes l15 spread over distinct banks (stride 17), quads broadcast
        unsigned int cw0 = sIdxW[(0 * 16 + l15) * 17 + sp];
        unsigned int cw1 = sIdxW[(1 * 16 + l15) * 17 + sp];
        unsigned int cw2 = sIdxW[(2 * 16 + l15) * 17 + sp];
        unsigned int cw3 = sIdxW[(3 * 16 + l15) * 17 + sp];

#pragma unroll
        for (int t = 0; t < 2; ++t) {           // step = sp*2 + t, k-base = step*32
            const int step = sp * 2 + t;

            // A fragments straight from L2 (16B contiguous per lane)
            half8_t a0 = *(const half8_t*)(abase + 0 * 16 * KG + step * 32);
            half8_t a1 = *(const half8_t*)(abase + 1 * 16 * KG + step * 32);

            // one-hot B from code byte (r12-verified build)
            unsigned int cws[4] = {cw0, cw1, cw2, cw3};
            half8_t b[4];
#pragma unroll
            for (int cf = 0; cf < 4; ++cf) {
                int code = (int)((cws[cf] >> (shft + 16 * t)) & 0xffu);
                int p = code - kpar8;
                int h = p >> 1;                 // negatives never match
                unsigned int sel = (p & 1) ? 0x3C000000u : 0x00003C00u;
                uint4 bw;
                bw.x = (h == 0) ? sel : 0u;
                bw.y = (h == 1) ? sel : 0u;
                bw.z = (h == 2) ? sel : 0u;
                bw.w = (h == 3) ? sel : 0u;
                b[cf] = *(half8_t*)&bw;
            }

#pragma unroll
            for (int cf = 0; cf < 4; ++cf) {
                acc[0][cf] = __builtin_amdgcn_mfma_f32_16x16x32_f16(a0, b[cf], acc[0][cf], 0, 0, 0);
                acc[1][cf] = __builtin_amdgcn_mfma_f32_16x16x32_f16(a1, b[cf], acc[1][cf], 0, 0, 0);
            }
        }
    }

    // ---- epilogue (r12-verified D layout: col=l15 -> j, row=quad*4+reg -> m)
#pragma unroll
    for (int rf = 0; rf < 2; ++rf)
#pragma unroll
        for (int cf = 0; cf < 4; ++cf) {
            int j = j0 + cf * 16 + l15;
            int m = m0 + mw + rf * 16 + quad * 4;
            *(float4*)(out + (size_t)j * MM + m) =
                make_float4(acc[rf][cf][0], acc[rf][cf][1], acc[rf][cf][2], acc[rf][cf][3]);
        }
}

// ---------------------------------------------------------------------------
extern "C" void kernel_launch(void* const* d_in, const int* in_sizes, int n_in,
                              void* d_out, int out_size, void* d_ws, size_t ws_size,
                              hipStream_t stream) {
    const float* I = (const float*)d_in[0];  // (N, D) fp32
    const float* A = (const float*)d_in[1];  // (C, 8, 4) fp32
    const float* T = (const float*)d_in[2];  // (C*15,) fp32
    const float* L = (const float*)d_in[3];  // (M, C, K) fp32
    // d_in[4] = S, d_in[5] = B: structural constants, hard-coded.

    __half* Lh = (__half*)d_ws;                                   // 1 MB fp16 LUT, native layout
    unsigned char* idx = (unsigned char*)d_ws + (1 << 20);        // 1 MB codes
    float* out = (float*)d_out;                                   // (N, M) fp32

    hipLaunchKernelGGL(convert_lut, dim3((MM * KG / 4) / 256), dim3(256), 0, stream, L, Lh);
    hipLaunchKernelGGL(encode_kernel, dim3((NN * CC) / 256), dim3(256), 0, stream, I, A, T, idx);
    hipLaunchKernelGGL(gemm_decode, dim3((MM / BM) * (NN / BJ)), dim3(256), 0, stream, Lh, idx, out);
}